// Round 4
// baseline (575.454 us; speedup 1.0000x reference)
//
#include <hip/hip_runtime.h>
#include <hip/hip_bf16.h>
#include <math.h>

#define N_EXPERTS 8
#define TOPK      2
#define IN_DIM    512
#define HID_DIM   1024
#define OUT_DIM   512
#define B_TOKENS  16384
#define NPAIRS    (B_TOKENS * TOPK)   // 32768 token-expert pairs (fixed!)
#define RB64      528                 // 64-row blocks covering padded rows (33792/64)
#define MAX_ROWS  (RB64 * 64)         // 33792

typedef __attribute__((ext_vector_type(8))) short short8;   // 8 bf16
typedef __attribute__((ext_vector_type(4))) float floatx4;

// ---- workspace layout (bytes) ----
#define WS_CNT     0          // 8 int
#define WS_CURSOR  32         // 8 int
#define WS_OFFS    64         // 9 int
#define WS_RBE     128        // 528 int (expert id per 64-row block)
#define WS_TKIDX   2304       // 32768 int
#define WS_TKW     133376     // 32768 float
#define WS_ROWS    264448     // 33792 int
#define WS_WPOS    399616     // 33792 float
#define WS_W1T     534784     // 8*1024*512 bf16 = 8 MB
#define WS_W2T     8923392    // 8*512*1024 bf16 = 8 MB
// total ~17 MB

__device__ __forceinline__ short f2bf(float f) {
  unsigned u = __float_as_uint(f);
  unsigned r = (u + 0x7fffu + ((u >> 16) & 1u)) >> 16;  // RNE
  return (short)r;
}

// ---------------- weight transpose + fp32->bf16 ----------------
// src [E][R][C] fp32 -> dst [E][C][R] bf16
__global__ __launch_bounds__(256) void transpose_cvt(const float* __restrict__ src,
                                                     short* __restrict__ dst,
                                                     int R, int C) {
  __shared__ float tile[32][33];
  int e = blockIdx.z;
  int r0 = blockIdx.y * 32, c0 = blockIdx.x * 32;
  const float* s = src + (size_t)e * R * C;
  short* d = dst + (size_t)e * R * C;
  int tr = threadIdx.x >> 5, tc = threadIdx.x & 31;
#pragma unroll
  for (int j = 0; j < 4; ++j)
    tile[tr + j * 8][tc] = s[(size_t)(r0 + tr + j * 8) * C + c0 + tc];
  __syncthreads();
#pragma unroll
  for (int j = 0; j < 4; ++j)
    d[(size_t)(c0 + tr + j * 8) * R + r0 + tc] = f2bf(tile[tc][tr + j * 8]);
}

// ---------------- gate: fp32 scores, top-2, softmax, counts ----------------
__global__ __launch_bounds__(256) void gate_kernel(const float* __restrict__ x,
                                                   const float* __restrict__ gw,
                                                   const float* __restrict__ gb,
                                                   int* __restrict__ tkidx,
                                                   float* __restrict__ tkw,
                                                   int* __restrict__ cnt) {
  __shared__ int lds_cnt[N_EXPERTS];
  if (threadIdx.x < N_EXPERTS) lds_cnt[threadIdx.x] = 0;
  __syncthreads();
  int w = threadIdx.x >> 6, lane = threadIdx.x & 63;
#pragma unroll 1
  for (int q = 0; q < 4; ++q) {
    int t = blockIdx.x * 16 + w * 4 + q;
    float s[8] = {0.f, 0.f, 0.f, 0.f, 0.f, 0.f, 0.f, 0.f};
#pragma unroll
    for (int it = 0; it < 8; ++it) {
      int i = it * 64 + lane;
      float xv = x[(size_t)t * IN_DIM + i];
      const float4* gwr = (const float4*)(gw + (size_t)i * 8);
      float4 g0 = gwr[0], g1 = gwr[1];
      s[0] += xv * g0.x; s[1] += xv * g0.y; s[2] += xv * g0.z; s[3] += xv * g0.w;
      s[4] += xv * g1.x; s[5] += xv * g1.y; s[6] += xv * g1.z; s[7] += xv * g1.w;
    }
#pragma unroll
    for (int off = 32; off > 0; off >>= 1) {
#pragma unroll
      for (int j = 0; j < 8; ++j) s[j] += __shfl_xor(s[j], off);
    }
    if (lane == 0) {
      float v[8];
#pragma unroll
      for (int j = 0; j < 8; ++j) v[j] = s[j] + gb[j];
      int i1 = 0; float v1 = v[0];
#pragma unroll
      for (int j = 1; j < 8; ++j) if (v[j] > v1) { v1 = v[j]; i1 = j; }
      int i2 = -1; float v2 = -1e30f;
#pragma unroll
      for (int j = 0; j < 8; ++j) if (j != i1 && v[j] > v2) { v2 = v[j]; i2 = j; }
      float ex = expf(v2 - v1);
      float wa = 1.0f / (1.0f + ex);
      tkidx[t * 2] = i1; tkidx[t * 2 + 1] = i2;
      tkw[t * 2] = wa;  tkw[t * 2 + 1] = ex * wa;
      atomicAdd(&lds_cnt[i1], 1); atomicAdd(&lds_cnt[i2], 1);
    }
  }
  __syncthreads();
  if (threadIdx.x < N_EXPERTS) atomicAdd(&cnt[threadIdx.x], lds_cnt[threadIdx.x]);
}

// ---------------- offsets (padded to 128), rbe per 64-row block, pad zero, aux ----------------
__global__ __launch_bounds__(256) void offsets_kernel(const int* __restrict__ cnt,
                                                      int* __restrict__ offs,
                                                      int* __restrict__ rbe,
                                                      int* __restrict__ rows,
                                                      float* __restrict__ wpos,
                                                      float* __restrict__ aux_out) {
  __shared__ int off[N_EXPERTS + 1];
  if (threadIdx.x == 0) {
    int o = 0;
    float aux = 0.f;
    for (int e = 0; e < N_EXPERTS; ++e) {
      off[e] = o;
      o += (cnt[e] + 127) & ~127;
      float d = (float)cnt[e] / (float)NPAIRS - 1.0f / N_EXPERTS;
      aux += d * d;
    }
    off[N_EXPERTS] = o;
    aux_out[0] = aux / N_EXPERTS;
  }
  __syncthreads();
  if (threadIdx.x < N_EXPERTS + 1) offs[threadIdx.x] = off[threadIdx.x];
  for (int b = threadIdx.x; b < RB64; b += 256) {
    int r = b * 64, e = -1;
    for (int j = 0; j < N_EXPERTS; ++j)
      if (r >= off[j] && r < off[j + 1]) e = j;
    rbe[b] = e;
  }
  // zero pad entries so the fused epilogue is branch-free (weight 0 -> adds 0)
  for (int idx = threadIdx.x; idx < N_EXPERTS * 128; idx += 256) {
    int e = idx >> 7, sl = idx & 127;
    int p = off[e] + cnt[e] + sl;
    if (p < off[e + 1]) { rows[p] = 0; wpos[p] = 0.f; }
  }
}

// ---------------- rank: block-aggregated position assignment (8 atomics/block) ----------------
__global__ __launch_bounds__(1024) void rank_kernel(const int* __restrict__ tkidx,
                                                    const float* __restrict__ tkw,
                                                    const int* __restrict__ offs,
                                                    int* __restrict__ cursor,
                                                    int* __restrict__ rows,
                                                    float* __restrict__ wpos) {
  __shared__ int wave_cnt[16][N_EXPERTS];
  __shared__ int wave_base[16][N_EXPERTS];
  __shared__ int blk_base[N_EXPERTS];
  const int tid = threadIdx.x, lane = tid & 63, w = tid >> 6;
  const int pr = blockIdx.x * 1024 + tid;
  const int e = tkidx[pr];
  int myrank = 0;
#pragma unroll
  for (int ei = 0; ei < N_EXPERTS; ++ei) {
    unsigned long long m = __ballot(e == ei);
    if (e == ei) myrank = __popcll(m & ((1ull << lane) - 1ull));
    if (lane == 0) wave_cnt[w][ei] = __popcll(m);
  }
  __syncthreads();
  if (tid < N_EXPERTS) {
    int base = 0;
#pragma unroll
    for (int ww = 0; ww < 16; ++ww) { wave_base[ww][tid] = base; base += wave_cnt[ww][tid]; }
    blk_base[tid] = atomicAdd(&cursor[tid], base);
  }
  __syncthreads();
  const int p = offs[e] + blk_base[e] + wave_base[w][e] + myrank;
  rows[p] = pr >> 1;
  wpos[p] = tkw[pr];
}

// ---------------- fused MoE FFN: per block = 64 grouped rows, full 512->1024->512 ----------------
// Phase A: stage x rows (fp32->bf16) into swizzled LDS (64x512).
// Per hc (8 chunks of 128 hidden cols):
//   P1: Hc = gelu(A @ W1[:,chunk] + b1)  - W1 B-frags direct from global (16 rows x 64B lines)
//   Hc -> padded LDS (C-layout write, A-layout read)
//   P2: accO += Hc @ W2[chunk,:]         - W2 B-frags direct from global
// Epilogue: atomicAdd(out[tok], wt * (accO + b2)).
__global__ __launch_bounds__(256, 2) void fused_moe(const float* __restrict__ x,
                                                    const short* __restrict__ w1t,
                                                    const float* __restrict__ b1,
                                                    const short* __restrict__ w2t,
                                                    const float* __restrict__ b2,
                                                    const int* __restrict__ rbe,
                                                    const int* __restrict__ rows,
                                                    const float* __restrict__ wpos,
                                                    float* __restrict__ out) {
  const int e = rbe[blockIdx.x];
  if (e < 0) return;
  const int row0 = blockIdx.x * 64;
  __shared__ short As[64 * 512];    // 64 KB, xor-swizzled 16B chunks
  __shared__ short Hs[64 * 136];    // 17 KB, row-major padded (+8 shorts)
  const int tid = threadIdx.x, lane = tid & 63, w = tid >> 6;
  const int mlow = lane & 15, quad = lane >> 4;
  const int wm = w & 1, wn = w >> 1;

  // ---- stage A ----
#pragma unroll 4
  for (int i = tid; i < 64 * 64; i += 256) {
    int r = i >> 6, kc = i & 63;
    int tok = rows[row0 + r];
    const float4* src = (const float4*)(x + (size_t)tok * IN_DIM + kc * 8);
    float4 v0 = src[0], v1 = src[1];
    short8 o;
    o[0] = f2bf(v0.x); o[1] = f2bf(v0.y); o[2] = f2bf(v0.z); o[3] = f2bf(v0.w);
    o[4] = f2bf(v1.x); o[5] = f2bf(v1.y); o[6] = f2bf(v1.z); o[7] = f2bf(v1.w);
    *(short8*)(As + ((r * 64) + (kc ^ (r & 7))) * 8) = o;
  }

  floatx4 accO[4][8] = {};
  const short* W1e = w1t + (size_t)e * HID_DIM * IN_DIM;
  const short* W2e = w2t + (size_t)e * OUT_DIM * HID_DIM;
  const float* b1e = b1 + (size_t)e * HID_DIM;

  __syncthreads();

#pragma unroll 1
  for (int hc = 0; hc < 8; ++hc) {
    // ---- P1: Hc(64x128) = A(64x512) @ W1chunk^T ----
    floatx4 acc1[2][4] = {};
    const short* w1base = W1e + (size_t)(hc * 128 + wn * 64 + mlow) * IN_DIM + quad * 8;
    short8 bcur[4];
#pragma unroll
    for (int nj = 0; nj < 4; ++nj)
      bcur[nj] = *(const short8*)(w1base + nj * 16 * IN_DIM);
#pragma unroll 1
    for (int kk = 0; kk < 16; ++kk) {
      short8 bn[4], a[2];
      if (kk < 15) {
#pragma unroll
        for (int nj = 0; nj < 4; ++nj)
          bn[nj] = *(const short8*)(w1base + nj * 16 * IN_DIM + (kk + 1) * 32);
      }
#pragma unroll
      for (int mi = 0; mi < 2; ++mi) {
        int r = wm * 32 + mi * 16 + mlow;
        int kc = kk * 4 + quad;
        a[mi] = *(const short8*)(As + (r * 64 + (kc ^ (r & 7))) * 8);
      }
#pragma unroll
      for (int mi = 0; mi < 2; ++mi)
#pragma unroll
        for (int nj = 0; nj < 4; ++nj)
          acc1[mi][nj] = __builtin_amdgcn_mfma_f32_16x16x32_bf16(a[mi], bcur[nj], acc1[mi][nj], 0, 0, 0);
#pragma unroll
      for (int nj = 0; nj < 4; ++nj) bcur[nj] = bn[nj];
    }
    __syncthreads();   // WAR: prev hc's P2 reads of Hs complete
    // ---- gelu -> Hs ----
#pragma unroll
    for (int mi = 0; mi < 2; ++mi)
#pragma unroll
      for (int nj = 0; nj < 4; ++nj) {
        int col = wn * 64 + nj * 16 + mlow;
        float bv = b1e[hc * 128 + col];
#pragma unroll
        for (int r = 0; r < 4; ++r) {
          int row = wm * 32 + mi * 16 + quad * 4 + r;
          float hval = acc1[mi][nj][r] + bv;
          float g = 0.5f * hval * (1.0f + erff(hval * 0.70710678118654752f));
          Hs[row * 136 + col] = f2bf(g);
        }
      }
    __syncthreads();   // Hs visible
    // ---- P2: accO(64x512) += Hc(64x128) @ W2chunk^T ----
#pragma unroll 1
    for (int k2 = 0; k2 < 4; ++k2) {
      short8 a2[4], bf[8];
      const short* w2base = W2e + (size_t)(w * 128 + mlow) * HID_DIM + hc * 128 + k2 * 32 + quad * 8;
#pragma unroll
      for (int nj = 0; nj < 8; ++nj)
        bf[nj] = *(const short8*)(w2base + (size_t)nj * 16 * HID_DIM);
#pragma unroll
      for (int mt = 0; mt < 4; ++mt)
        a2[mt] = *(const short8*)(Hs + (mt * 16 + mlow) * 136 + k2 * 32 + quad * 8);
#pragma unroll
      for (int mt = 0; mt < 4; ++mt)
#pragma unroll
        for (int nj = 0; nj < 8; ++nj)
          accO[mt][nj] = __builtin_amdgcn_mfma_f32_16x16x32_bf16(a2[mt], bf[nj], accO[mt][nj], 0, 0, 0);
    }
  }

  // ---- epilogue ----
  const float* b2e = b2 + (size_t)e * OUT_DIM;
#pragma unroll
  for (int mt = 0; mt < 4; ++mt) {
#pragma unroll
    for (int r = 0; r < 4; ++r) {
      int p = row0 + mt * 16 + quad * 4 + r;
      int tok = rows[p];
      float wt = wpos[p];
#pragma unroll
      for (int nj = 0; nj < 8; ++nj) {
        int col = w * 128 + nj * 16 + mlow;
        float val = wt * (accO[mt][nj][r] + b2e[col]);
        atomicAdd(out + (size_t)tok * OUT_DIM + col, val);
      }
    }
  }
}

extern "C" void kernel_launch(void* const* d_in, const int* in_sizes, int n_in,
                              void* d_out, int out_size, void* d_ws, size_t ws_size,
                              hipStream_t stream) {
  const float* x      = (const float*)d_in[0];
  const float* gate_w = (const float*)d_in[1];
  const float* gate_b = (const float*)d_in[2];
  const float* w1     = (const float*)d_in[3];
  const float* b1     = (const float*)d_in[4];
  const float* w2     = (const float*)d_in[5];
  const float* b2     = (const float*)d_in[6];
  float* out = (float*)d_out;
  char* ws = (char*)d_ws;

  int*   cnt    = (int*)(ws + WS_CNT);
  int*   cursor = (int*)(ws + WS_CURSOR);
  int*   offs   = (int*)(ws + WS_OFFS);
  int*   rbe    = (int*)(ws + WS_RBE);
  int*   tkidx  = (int*)(ws + WS_TKIDX);
  float* tkw    = (float*)(ws + WS_TKW);
  int*   rows   = (int*)(ws + WS_ROWS);
  float* wpos   = (float*)(ws + WS_WPOS);
  short* w1t    = (short*)(ws + WS_W1T);
  short* w2t    = (short*)(ws + WS_W2T);

  hipMemsetAsync(ws, 0, 128, stream);                                    // cnt+cursor+offs
  hipMemsetAsync(d_out, 0, (size_t)out_size * sizeof(float), stream);    // out accumulated by atomics

  transpose_cvt<<<dim3(HID_DIM / 32, IN_DIM / 32, N_EXPERTS), 256, 0, stream>>>(w1, w1t, IN_DIM, HID_DIM);
  transpose_cvt<<<dim3(OUT_DIM / 32, HID_DIM / 32, N_EXPERTS), 256, 0, stream>>>(w2, w2t, HID_DIM, OUT_DIM);

  gate_kernel<<<B_TOKENS / 16, 256, 0, stream>>>(x, gate_w, gate_b, tkidx, tkw, cnt);

  offsets_kernel<<<1, 256, 0, stream>>>(cnt, offs, rbe, rows, wpos, out + (size_t)B_TOKENS * OUT_DIM);

  rank_kernel<<<NPAIRS / 1024, 1024, 0, stream>>>(tkidx, tkw, offs, cursor, rows, wpos);

  fused_moe<<<RB64, 256, 0, stream>>>(x, w1t, b1, w2t, b2, rbe, rows, wpos, out);
}

// Round 5
// 510.401 us; speedup vs baseline: 1.1275x; 1.1275x over previous
//
#include <hip/hip_runtime.h>
#include <hip/hip_bf16.h>
#include <math.h>

#define N_EXPERTS 8
#define TOPK      2
#define IN_DIM    512
#define HID_DIM   1024
#define OUT_DIM   512
#define B_TOKENS  16384
#define NPAIRS    (B_TOKENS * TOPK)   // 32768 token-expert pairs (fixed!)
#define MAX_RB    264                 // 128-row blocks after per-expert pad
#define MAX_ROWS  (MAX_RB * 128)      // 33792

typedef __attribute__((ext_vector_type(8))) short short8;   // 8 bf16
typedef __attribute__((ext_vector_type(4))) float floatx4;

// ---- workspace layout (bytes) ----
#define WS_CNT     0          // 8 int
#define WS_CURSOR  32         // 8 int
#define WS_OFFS    64         // 9 int
#define WS_RBE     128        // 264 int
#define WS_TKIDX   1280       // 32768 int
#define WS_TKW     132352     // 32768 float
#define WS_ROWS    263424     // 33792 int
#define WS_WPOS    398592     // 33792 float
#define WS_W1T     533760     // 8*1024*512 bf16 = 8 MB
#define WS_W2T     8922368    // 8*512*1024 bf16 = 8 MB
#define WS_XBF     17310976   // 16384*512 bf16  = 16.8 MB
#define WS_H       34088192   // 33792*1024 bf16 = 69.2 MB
// total ~103.3 MB

__device__ __forceinline__ short f2bf(float f) {
  unsigned u = __float_as_uint(f);
  unsigned r = (u + 0x7fffu + ((u >> 16) & 1u)) >> 16;  // RNE
  return (short)r;
}

__device__ __forceinline__ void async16(const void* g, void* l) {
  __builtin_amdgcn_global_load_lds(
      (const __attribute__((address_space(1))) unsigned*)g,
      (__attribute__((address_space(3))) unsigned*)l, 16, 0, 0);
}

// ---------------- cvt_x: x fp32 -> bf16, streaming ----------------
__global__ __launch_bounds__(256) void cvt_x(const float* __restrict__ x,
                                             short* __restrict__ xbf) {
  int i = (blockIdx.x * 256 + threadIdx.x) * 8;
  const float4* src = (const float4*)(x + i);
  float4 v0 = src[0], v1 = src[1];
  short8 o;
  o[0] = f2bf(v0.x); o[1] = f2bf(v0.y); o[2] = f2bf(v0.z); o[3] = f2bf(v0.w);
  o[4] = f2bf(v1.x); o[5] = f2bf(v1.y); o[6] = f2bf(v1.z); o[7] = f2bf(v1.w);
  *(short8*)(xbf + i) = o;
}

// ---------------- weight transpose + fp32->bf16 ----------------
// src [E][R][C] fp32 -> dst [E][C][R] bf16
__global__ __launch_bounds__(256) void transpose_cvt(const float* __restrict__ src,
                                                     short* __restrict__ dst,
                                                     int R, int C) {
  __shared__ float tile[32][33];
  int e = blockIdx.z;
  int r0 = blockIdx.y * 32, c0 = blockIdx.x * 32;
  const float* s = src + (size_t)e * R * C;
  short* d = dst + (size_t)e * R * C;
  int tr = threadIdx.x >> 5, tc = threadIdx.x & 31;
#pragma unroll
  for (int j = 0; j < 4; ++j)
    tile[tr + j * 8][tc] = s[(size_t)(r0 + tr + j * 8) * C + c0 + tc];
  __syncthreads();
#pragma unroll
  for (int j = 0; j < 4; ++j)
    d[(size_t)(c0 + tr + j * 8) * R + r0 + tc] = f2bf(tile[tc][tr + j * 8]);
}

// ---------------- gate: fp32 scores, top-2, softmax, counts ----------------
__global__ __launch_bounds__(256) void gate_kernel(const float* __restrict__ x,
                                                   const float* __restrict__ gw,
                                                   const float* __restrict__ gb,
                                                   int* __restrict__ tkidx,
                                                   float* __restrict__ tkw,
                                                   int* __restrict__ cnt) {
  __shared__ int lds_cnt[N_EXPERTS];
  if (threadIdx.x < N_EXPERTS) lds_cnt[threadIdx.x] = 0;
  __syncthreads();
  int w = threadIdx.x >> 6, lane = threadIdx.x & 63;
#pragma unroll 1
  for (int q = 0; q < 4; ++q) {
    int t = blockIdx.x * 16 + w * 4 + q;
    float s[8] = {0.f, 0.f, 0.f, 0.f, 0.f, 0.f, 0.f, 0.f};
#pragma unroll
    for (int it = 0; it < 8; ++it) {
      int i = it * 64 + lane;
      float xv = x[(size_t)t * IN_DIM + i];
      const float4* gwr = (const float4*)(gw + (size_t)i * 8);
      float4 g0 = gwr[0], g1 = gwr[1];
      s[0] += xv * g0.x; s[1] += xv * g0.y; s[2] += xv * g0.z; s[3] += xv * g0.w;
      s[4] += xv * g1.x; s[5] += xv * g1.y; s[6] += xv * g1.z; s[7] += xv * g1.w;
    }
#pragma unroll
    for (int off = 32; off > 0; off >>= 1) {
#pragma unroll
      for (int j = 0; j < 8; ++j) s[j] += __shfl_xor(s[j], off);
    }
    if (lane == 0) {
      float v[8];
#pragma unroll
      for (int j = 0; j < 8; ++j) v[j] = s[j] + gb[j];
      int i1 = 0; float v1 = v[0];
#pragma unroll
      for (int j = 1; j < 8; ++j) if (v[j] > v1) { v1 = v[j]; i1 = j; }
      int i2 = -1; float v2 = -1e30f;
#pragma unroll
      for (int j = 0; j < 8; ++j) if (j != i1 && v[j] > v2) { v2 = v[j]; i2 = j; }
      float ex = expf(v2 - v1);
      float wa = 1.0f / (1.0f + ex);
      tkidx[t * 2] = i1; tkidx[t * 2 + 1] = i2;
      tkw[t * 2] = wa;  tkw[t * 2 + 1] = ex * wa;
      atomicAdd(&lds_cnt[i1], 1); atomicAdd(&lds_cnt[i2], 1);
    }
  }
  __syncthreads();
  if (threadIdx.x < N_EXPERTS) atomicAdd(&cnt[threadIdx.x], lds_cnt[threadIdx.x]);
}

// ---------------- offsets (padded to 128), rbe per 128-row block, pad zero, aux ----------------
__global__ __launch_bounds__(256) void offsets_kernel(const int* __restrict__ cnt,
                                                      int* __restrict__ offs,
                                                      int* __restrict__ rbe,
                                                      int* __restrict__ rows,
                                                      float* __restrict__ wpos,
                                                      float* __restrict__ aux_out) {
  __shared__ int off[N_EXPERTS + 1];
  if (threadIdx.x == 0) {
    int o = 0;
    float aux = 0.f;
    for (int e = 0; e < N_EXPERTS; ++e) {
      off[e] = o;
      o += (cnt[e] + 127) & ~127;
      float d = (float)cnt[e] / (float)NPAIRS - 1.0f / N_EXPERTS;
      aux += d * d;
    }
    off[N_EXPERTS] = o;
    aux_out[0] = aux / N_EXPERTS;
  }
  __syncthreads();
  if (threadIdx.x < N_EXPERTS + 1) offs[threadIdx.x] = off[threadIdx.x];
  for (int b = threadIdx.x; b < MAX_RB; b += 256) {
    int r = b * 128, e = -1;
    for (int j = 0; j < N_EXPERTS; ++j)
      if (r >= off[j] && r < off[j + 1]) e = j;
    rbe[b] = e;
  }
  // zero pad entries so epilogues are branch-free (weight 0 -> adds 0)
  for (int idx = threadIdx.x; idx < N_EXPERTS * 128; idx += 256) {
    int e = idx >> 7, sl = idx & 127;
    int p = off[e] + cnt[e] + sl;
    if (p < off[e + 1]) { rows[p] = 0; wpos[p] = 0.f; }
  }
}

// ---------------- rank: block-aggregated position assignment (8 atomics/block) ----------------
__global__ __launch_bounds__(1024) void rank_kernel(const int* __restrict__ tkidx,
                                                    const float* __restrict__ tkw,
                                                    const int* __restrict__ offs,
                                                    int* __restrict__ cursor,
                                                    int* __restrict__ rows,
                                                    float* __restrict__ wpos) {
  __shared__ int wave_cnt[16][N_EXPERTS];
  __shared__ int wave_base[16][N_EXPERTS];
  __shared__ int blk_base[N_EXPERTS];
  const int tid = threadIdx.x, lane = tid & 63, w = tid >> 6;
  const int pr = blockIdx.x * 1024 + tid;
  const int e = tkidx[pr];
  int myrank = 0;
#pragma unroll
  for (int ei = 0; ei < N_EXPERTS; ++ei) {
    unsigned long long m = __ballot(e == ei);
    if (e == ei) myrank = __popcll(m & ((1ull << lane) - 1ull));
    if (lane == 0) wave_cnt[w][ei] = __popcll(m);
  }
  __syncthreads();
  if (tid < N_EXPERTS) {
    int base = 0;
#pragma unroll
    for (int ww = 0; ww < 16; ++ww) { wave_base[ww][tid] = base; base += wave_cnt[ww][tid]; }
    blk_base[tid] = atomicAdd(&cursor[tid], base);
  }
  __syncthreads();
  const int p = offs[e] + blk_base[e] + wave_base[w][e] + myrank;
  rows[p] = pr >> 1;
  wpos[p] = tkw[pr];
}

// ---------------- grouped GEMM: 128x256 tile, BK=64, async16 staging ----------------
// Fragment-major LDS: chunk c holds 16B of (tile row, k-granule); staging instr j
// writes chunk c = j*256+tid (lane-linear, per m104's wave-uniform-base rule);
// source decoded from c: tile-row = (c>>7)*16 + (c&15), k-granule = (c>>4)&7.
// GATHER=1: A rows come from xbf via rows[] (per-lane global addresses are fine).
// MODE 0: H = gelu(A @ W1[e] + b1[e]) -> bf16     (KD=512,  ND=1024)
// MODE 1: atomicAdd(out[tok], w * (A @ W2[e] + b2[e]))   (KD=1024, ND=512)
template <int KD, int ND, int MODE, int GATHER>
__global__ __launch_bounds__(256) void moe_gemm(const short* __restrict__ Asrc,
                                                const short* __restrict__ Bmat,
                                                const float* __restrict__ bias,
                                                const int* __restrict__ rbe,
                                                const int* __restrict__ rows,
                                                const float* __restrict__ wpos,
                                                short* __restrict__ Hout,
                                                float* __restrict__ Oout) {
  constexpr int NBN = ND / 256;
  // XCD swizzle: bid&7 = XCD (round-robin heuristic). Each XCD owns a slab of
  // 33 contiguous row-blocks x all N-blocks -> weights ~1 expert/XCD-L2,
  // A-tiles re-read within one XCD.
  const int bid = blockIdx.x;
  const int xcd = bid & 7, slab = bid >> 3;
  const int by = xcd * (MAX_RB / 8) + slab / NBN;
  const int bx = slab % NBN;
  const int e = rbe[by];
  if (e < 0) return;
  const int row0 = by * 128;
  const int n0 = bx * 256;

  __shared__ short As[128 * 64];   // 16 KB
  __shared__ short Bs[256 * 64];   // 32 KB
  const int tid = threadIdx.x;
  const int lane = tid & 63, w = tid >> 6;
  const int wm = w & 1, wn = w >> 1;
  const int mlow = lane & 15, quad = lane >> 4;

  floatx4 acc[4][8] = {};

  // staging source decode (chunk c = j*256 + tid)
  const int hi = tid >> 7;              // (c>>7) = 2j + hi
  const int kidx = (tid >> 4) & 7;      // k-granule, j-invariant
  const int slow = tid & 15;
  const short* gA[4];
#pragma unroll
  for (int j = 0; j < 4; ++j) {
    int r = row0 + (2 * j + hi) * 16 + slow;
    int src_row = GATHER ? rows[r] : r;
    gA[j] = Asrc + (size_t)src_row * KD + kidx * 8;
  }
  const short* gB = Bmat + (size_t)e * ND * KD + (size_t)(n0 + hi * 16 + slow) * KD + kidx * 8;
  short* lA = As + tid * 8;
  short* lB = Bs + tid * 8;

  const short* ab = As + ((size_t)wm * 512 + quad * 16 + mlow) * 8;
  const short* bb = Bs + ((size_t)wn * 1024 + quad * 16 + mlow) * 8;

  for (int k0 = 0; k0 < KD; k0 += 64) {
    __syncthreads();                    // WAR: prev frag reads done
#pragma unroll
    for (int j = 0; j < 4; ++j)
      async16(gA[j] + k0, lA + j * 2048);
#pragma unroll
    for (int j = 0; j < 8; ++j)
      async16(gB + (size_t)j * 32 * KD + k0, lB + j * 2048);
    __syncthreads();                    // drains vmcnt before barrier
#pragma unroll
    for (int kk = 0; kk < 2; ++kk) {
      short8 a[4], b[8];
#pragma unroll
      for (int t = 0; t < 4; ++t)
        a[t] = *(const short8*)(ab + (t * 128 + kk * 64) * 8);
#pragma unroll
      for (int u = 0; u < 8; ++u)
        b[u] = *(const short8*)(bb + (u * 128 + kk * 64) * 8);
#pragma unroll
      for (int t = 0; t < 4; ++t)
#pragma unroll
        for (int u = 0; u < 8; ++u)
          acc[t][u] = __builtin_amdgcn_mfma_f32_16x16x32_bf16(a[t], b[u], acc[t][u], 0, 0, 0);
    }
  }

  const float* be = bias + (size_t)e * ND;
  if (MODE == 0) {
#pragma unroll
    for (int t = 0; t < 4; ++t) {
      int gr = row0 + wm * 64 + t * 16 + quad * 4;
#pragma unroll
      for (int u = 0; u < 8; ++u) {
        int gc = n0 + wn * 128 + u * 16 + mlow;
        float bv = be[gc];
#pragma unroll
        for (int r = 0; r < 4; ++r) {
          float h = acc[t][u][r] + bv;
          float g = 0.5f * h * (1.0f + erff(h * 0.70710678118654752f));
          Hout[(size_t)(gr + r) * ND + gc] = f2bf(g);
        }
      }
    }
  } else {
#pragma unroll
    for (int t = 0; t < 4; ++t) {
      int pr = row0 + wm * 64 + t * 16 + quad * 4;
#pragma unroll
      for (int r = 0; r < 4; ++r) {
        int p = pr + r;
        int tok = rows[p];
        float wt = wpos[p];
#pragma unroll
        for (int u = 0; u < 8; ++u) {
          int gc = n0 + wn * 128 + u * 16 + mlow;
          float val = wt * (acc[t][u][r] + be[gc]);
          atomicAdd(Oout + (size_t)tok * OUT_DIM + gc, val);
        }
      }
    }
  }
}

extern "C" void kernel_launch(void* const* d_in, const int* in_sizes, int n_in,
                              void* d_out, int out_size, void* d_ws, size_t ws_size,
                              hipStream_t stream) {
  const float* x      = (const float*)d_in[0];
  const float* gate_w = (const float*)d_in[1];
  const float* gate_b = (const float*)d_in[2];
  const float* w1     = (const float*)d_in[3];
  const float* b1     = (const float*)d_in[4];
  const float* w2     = (const float*)d_in[5];
  const float* b2     = (const float*)d_in[6];
  float* out = (float*)d_out;
  char* ws = (char*)d_ws;

  int*   cnt    = (int*)(ws + WS_CNT);
  int*   cursor = (int*)(ws + WS_CURSOR);
  int*   offs   = (int*)(ws + WS_OFFS);
  int*   rbe    = (int*)(ws + WS_RBE);
  int*   tkidx  = (int*)(ws + WS_TKIDX);
  float* tkw    = (float*)(ws + WS_TKW);
  int*   rows   = (int*)(ws + WS_ROWS);
  float* wpos   = (float*)(ws + WS_WPOS);
  short* w1t    = (short*)(ws + WS_W1T);
  short* w2t    = (short*)(ws + WS_W2T);
  short* xbf    = (short*)(ws + WS_XBF);
  short* h      = (short*)(ws + WS_H);

  hipMemsetAsync(ws, 0, 128, stream);                                    // cnt+cursor+offs
  hipMemsetAsync(d_out, 0, (size_t)out_size * sizeof(float), stream);    // out accumulated by atomics

  cvt_x<<<B_TOKENS * IN_DIM / (256 * 8), 256, 0, stream>>>(x, xbf);

  transpose_cvt<<<dim3(HID_DIM / 32, IN_DIM / 32, N_EXPERTS), 256, 0, stream>>>(w1, w1t, IN_DIM, HID_DIM);
  transpose_cvt<<<dim3(OUT_DIM / 32, HID_DIM / 32, N_EXPERTS), 256, 0, stream>>>(w2, w2t, HID_DIM, OUT_DIM);

  gate_kernel<<<B_TOKENS / 16, 256, 0, stream>>>(x, gate_w, gate_b, tkidx, tkw, cnt);

  offsets_kernel<<<1, 256, 0, stream>>>(cnt, offs, rbe, rows, wpos, out + (size_t)B_TOKENS * OUT_DIM);

  rank_kernel<<<NPAIRS / 1024, 1024, 0, stream>>>(tkidx, tkw, offs, cursor, rows, wpos);

  moe_gemm<IN_DIM, HID_DIM, 0, 1><<<(HID_DIM / 256) * MAX_RB, 256, 0, stream>>>(
      xbf, w1t, b1, rbe, rows, wpos, h, nullptr);

  moe_gemm<HID_DIM, OUT_DIM, 1, 0><<<(OUT_DIM / 256) * MAX_RB, 256, 0, stream>>>(
      h, w2t, b2, rbe, rows, wpos, nullptr, out);
}

// Round 6
// 413.242 us; speedup vs baseline: 1.3925x; 1.2351x over previous
//
#include <hip/hip_runtime.h>
#include <hip/hip_bf16.h>
#include <math.h>

#define N_EXPERTS 8
#define TOPK      2
#define IN_DIM    512
#define HID_DIM   1024
#define OUT_DIM   512
#define B_TOKENS  16384
#define NPAIRS    (B_TOKENS * TOPK)   // 32768 token-expert pairs (fixed!)
#define MAX_RB    264                 // 128-row blocks after per-expert pad
#define MAX_ROWS  (MAX_RB * 128)      // 33792

typedef __attribute__((ext_vector_type(8))) short short8;   // 8 bf16
typedef __attribute__((ext_vector_type(4))) float floatx4;

// ---- workspace layout (bytes) ----
#define WS_CNT     0          // 8 int
#define WS_CURSOR  32         // 8 int
#define WS_OFFS    64         // 9 int
#define WS_RBE     128        // 264 int
#define WS_TKIDX   1280       // 32768 int
#define WS_TKW     132352     // 32768 float
#define WS_ROWS    263424     // 33792 int
#define WS_WPOS    398592     // 33792 float
#define WS_W1T     533760     // 8*1024*512 bf16 = 8 MB
#define WS_W2T     8922368    // 8*512*1024 bf16 = 8 MB
#define WS_XBF     17310976   // 16384*512 bf16  = 16.8 MB
#define WS_H       34088192   // 33792*1024 bf16 = 69.2 MB
// total ~103.3 MB

__device__ __forceinline__ short f2bf(float f) {
  unsigned u = __float_as_uint(f);
  unsigned r = (u + 0x7fffu + ((u >> 16) & 1u)) >> 16;  // RNE
  return (short)r;
}

__device__ __forceinline__ void async16(const void* g, void* l) {
  __builtin_amdgcn_global_load_lds(
      (const __attribute__((address_space(1))) unsigned*)g,
      (__attribute__((address_space(3))) unsigned*)l, 16, 0, 0);
}

// ---------------- cvt_x: x fp32 -> bf16, streaming ----------------
__global__ __launch_bounds__(256) void cvt_x(const float* __restrict__ x,
                                             short* __restrict__ xbf) {
  int i = (blockIdx.x * 256 + threadIdx.x) * 8;
  const float4* src = (const float4*)(x + i);
  float4 v0 = src[0], v1 = src[1];
  short8 o;
  o[0] = f2bf(v0.x); o[1] = f2bf(v0.y); o[2] = f2bf(v0.z); o[3] = f2bf(v0.w);
  o[4] = f2bf(v1.x); o[5] = f2bf(v1.y); o[6] = f2bf(v1.z); o[7] = f2bf(v1.w);
  *(short8*)(xbf + i) = o;
}

// ---------------- weight transpose + fp32->bf16 ----------------
// src [E][R][C] fp32 -> dst [E][C][R] bf16
__global__ __launch_bounds__(256) void transpose_cvt(const float* __restrict__ src,
                                                     short* __restrict__ dst,
                                                     int R, int C) {
  __shared__ float tile[32][33];
  int e = blockIdx.z;
  int r0 = blockIdx.y * 32, c0 = blockIdx.x * 32;
  const float* s = src + (size_t)e * R * C;
  short* d = dst + (size_t)e * R * C;
  int tr = threadIdx.x >> 5, tc = threadIdx.x & 31;
#pragma unroll
  for (int j = 0; j < 4; ++j)
    tile[tr + j * 8][tc] = s[(size_t)(r0 + tr + j * 8) * C + c0 + tc];
  __syncthreads();
#pragma unroll
  for (int j = 0; j < 4; ++j)
    d[(size_t)(c0 + tr + j * 8) * R + r0 + tc] = f2bf(tile[tc][tr + j * 8]);
}

// ---------------- gate: fp32 scores, top-2, softmax, counts ----------------
__global__ __launch_bounds__(256) void gate_kernel(const float* __restrict__ x,
                                                   const float* __restrict__ gw,
                                                   const float* __restrict__ gb,
                                                   int* __restrict__ tkidx,
                                                   float* __restrict__ tkw,
                                                   int* __restrict__ cnt) {
  __shared__ int lds_cnt[N_EXPERTS];
  if (threadIdx.x < N_EXPERTS) lds_cnt[threadIdx.x] = 0;
  __syncthreads();
  int w = threadIdx.x >> 6, lane = threadIdx.x & 63;
#pragma unroll 1
  for (int q = 0; q < 4; ++q) {
    int t = blockIdx.x * 16 + w * 4 + q;
    float s[8] = {0.f, 0.f, 0.f, 0.f, 0.f, 0.f, 0.f, 0.f};
#pragma unroll
    for (int it = 0; it < 8; ++it) {
      int i = it * 64 + lane;
      float xv = x[(size_t)t * IN_DIM + i];
      const float4* gwr = (const float4*)(gw + (size_t)i * 8);
      float4 g0 = gwr[0], g1 = gwr[1];
      s[0] += xv * g0.x; s[1] += xv * g0.y; s[2] += xv * g0.z; s[3] += xv * g0.w;
      s[4] += xv * g1.x; s[5] += xv * g1.y; s[6] += xv * g1.z; s[7] += xv * g1.w;
    }
#pragma unroll
    for (int off = 32; off > 0; off >>= 1) {
#pragma unroll
      for (int j = 0; j < 8; ++j) s[j] += __shfl_xor(s[j], off);
    }
    if (lane == 0) {
      float v[8];
#pragma unroll
      for (int j = 0; j < 8; ++j) v[j] = s[j] + gb[j];
      int i1 = 0; float v1 = v[0];
#pragma unroll
      for (int j = 1; j < 8; ++j) if (v[j] > v1) { v1 = v[j]; i1 = j; }
      int i2 = -1; float v2 = -1e30f;
#pragma unroll
      for (int j = 0; j < 8; ++j) if (j != i1 && v[j] > v2) { v2 = v[j]; i2 = j; }
      float ex = expf(v2 - v1);
      float wa = 1.0f / (1.0f + ex);
      tkidx[t * 2] = i1; tkidx[t * 2 + 1] = i2;
      tkw[t * 2] = wa;  tkw[t * 2 + 1] = ex * wa;
      atomicAdd(&lds_cnt[i1], 1); atomicAdd(&lds_cnt[i2], 1);
    }
  }
  __syncthreads();
  if (threadIdx.x < N_EXPERTS) atomicAdd(&cnt[threadIdx.x], lds_cnt[threadIdx.x]);
}

// ---------------- offsets (padded to 128), rbe per 128-row block, pad zero, aux ----------------
__global__ __launch_bounds__(256) void offsets_kernel(const int* __restrict__ cnt,
                                                      int* __restrict__ offs,
                                                      int* __restrict__ rbe,
                                                      int* __restrict__ rows,
                                                      float* __restrict__ wpos,
                                                      float* __restrict__ aux_out) {
  __shared__ int off[N_EXPERTS + 1];
  if (threadIdx.x == 0) {
    int o = 0;
    float aux = 0.f;
    for (int e = 0; e < N_EXPERTS; ++e) {
      off[e] = o;
      o += (cnt[e] + 127) & ~127;
      float d = (float)cnt[e] / (float)NPAIRS - 1.0f / N_EXPERTS;
      aux += d * d;
    }
    off[N_EXPERTS] = o;
    aux_out[0] = aux / N_EXPERTS;
  }
  __syncthreads();
  if (threadIdx.x < N_EXPERTS + 1) offs[threadIdx.x] = off[threadIdx.x];
  for (int b = threadIdx.x; b < MAX_RB; b += 256) {
    int r = b * 128, e = -1;
    for (int j = 0; j < N_EXPERTS; ++j)
      if (r >= off[j] && r < off[j + 1]) e = j;
    rbe[b] = e;
  }
  // zero pad entries so epilogues are branch-free (weight 0 -> adds 0)
  for (int idx = threadIdx.x; idx < N_EXPERTS * 128; idx += 256) {
    int e = idx >> 7, sl = idx & 127;
    int p = off[e] + cnt[e] + sl;
    if (p < off[e + 1]) { rows[p] = 0; wpos[p] = 0.f; }
  }
}

// ---------------- rank: block-aggregated position assignment (8 atomics/block) ----------------
__global__ __launch_bounds__(1024) void rank_kernel(const int* __restrict__ tkidx,
                                                    const float* __restrict__ tkw,
                                                    const int* __restrict__ offs,
                                                    int* __restrict__ cursor,
                                                    int* __restrict__ rows,
                                                    float* __restrict__ wpos) {
  __shared__ int wave_cnt[16][N_EXPERTS];
  __shared__ int wave_base[16][N_EXPERTS];
  __shared__ int blk_base[N_EXPERTS];
  const int tid = threadIdx.x, lane = tid & 63, w = tid >> 6;
  const int pr = blockIdx.x * 1024 + tid;
  const int e = tkidx[pr];
  int myrank = 0;
#pragma unroll
  for (int ei = 0; ei < N_EXPERTS; ++ei) {
    unsigned long long m = __ballot(e == ei);
    if (e == ei) myrank = __popcll(m & ((1ull << lane) - 1ull));
    if (lane == 0) wave_cnt[w][ei] = __popcll(m);
  }
  __syncthreads();
  if (tid < N_EXPERTS) {
    int base = 0;
#pragma unroll
    for (int ww = 0; ww < 16; ++ww) { wave_base[ww][tid] = base; base += wave_cnt[ww][tid]; }
    blk_base[tid] = atomicAdd(&cursor[tid], base);
  }
  __syncthreads();
  const int p = offs[e] + blk_base[e] + wave_base[w][e] + myrank;
  rows[p] = pr >> 1;
  wpos[p] = tkw[pr];
}

// ---------------- grouped GEMM: 128x128 tile, BK=64, double-buffered async16 ----------------
// acc 4x4 (64 AGPR) + ~110 VGPR -> 2+ waves/SIMD; LDS 64 KB -> 2 blocks/CU.
// Pipeline: barrier drains loads issued one compute-phase ago; next-buf loads
// issue immediately after the barrier, before MFMA -> latency hidden by compute.
// Fragment-major LDS, chunk c = j*256+tid: row=(c>>7)*16+(c&15), kgran=(c>>4)&7.
// GATHER=1: A rows gathered from xbf via rows[].
// MODE 0: H = gelu(A @ W1[e] + b1[e]) -> bf16     (KD=512,  ND=1024)
// MODE 1: atomicAdd(out[tok], w * (A @ W2[e] + b2[e]))   (KD=1024, ND=512)
template <int KD, int ND, int MODE, int GATHER>
__global__ __launch_bounds__(256) void moe_gemm(const short* __restrict__ Asrc,
                                                const short* __restrict__ Bmat,
                                                const float* __restrict__ bias,
                                                const int* __restrict__ rbe,
                                                const int* __restrict__ rows,
                                                const float* __restrict__ wpos,
                                                short* __restrict__ Hout,
                                                float* __restrict__ Oout) {
  constexpr int NBN = ND / 128;
  // XCD swizzle: bid&7 = XCD slot; each XCD owns a contiguous slab of row-blocks
  // so weights ~1 expert per XCD-L2 and A-tiles are re-read within one XCD.
  const int bid = blockIdx.x;
  const int xcd = bid & 7, slab = bid >> 3;
  const int by = xcd * (MAX_RB / 8) + slab / NBN;
  const int bx = slab % NBN;
  const int e = rbe[by];
  if (e < 0) return;
  const int row0 = by * 128;
  const int n0 = bx * 128;

  __shared__ short As[2][128 * 64];   // 2 x 16 KB
  __shared__ short Bs[2][128 * 64];   // 2 x 16 KB
  const int tid = threadIdx.x;
  const int lane = tid & 63, w = tid >> 6;
  const int wm = w & 1, wn = w >> 1;
  const int mlow = lane & 15, quad = lane >> 4;

  floatx4 acc[4][4] = {};

  // staging source decode (chunk c = j*256 + tid, j = 0..3)
  const int hi = tid >> 7;              // c>>7 = 2j + hi
  const int kgran = (tid >> 4) & 7;     // k-granule (8 shorts), j-invariant
  const int slow = tid & 15;
  const short* gA[4];
  const short* gB[4];
#pragma unroll
  for (int j = 0; j < 4; ++j) {
    int r = row0 + (2 * j + hi) * 16 + slow;
    int src_row = GATHER ? rows[r] : r;
    gA[j] = Asrc + (size_t)src_row * KD + kgran * 8;
    gB[j] = Bmat + (size_t)e * ND * KD +
            (size_t)(n0 + (2 * j + hi) * 16 + slow) * KD + kgran * 8;
  }
  const int ldst = tid * 8;             // shorts; lane-linear 16B chunks

  // prologue: fill buf 0
#pragma unroll
  for (int j = 0; j < 4; ++j) {
    async16(gA[j], &As[0][ldst + j * 2048]);
    async16(gB[j], &Bs[0][ldst + j * 2048]);
  }

  int buf = 0;
  for (int k0 = 0; k0 < KD; k0 += 64, buf ^= 1) {
    __syncthreads();   // drains loads for THIS buf (issued one compute-phase ago)
    const int kn = k0 + 64;
    if (kn < KD) {
#pragma unroll
      for (int j = 0; j < 4; ++j) {
        async16(gA[j] + kn, &As[buf ^ 1][ldst + j * 2048]);
        async16(gB[j] + kn, &Bs[buf ^ 1][ldst + j * 2048]);
      }
    }
#pragma unroll
    for (int kk = 0; kk < 2; ++kk) {
      short8 a[4], b[4];
#pragma unroll
      for (int t = 0; t < 4; ++t) {
        a[t] = *(const short8*)(&As[buf][((wm * 4 + t) * 128 + kk * 64 + quad * 16 + mlow) * 8]);
        b[t] = *(const short8*)(&Bs[buf][((wn * 4 + t) * 128 + kk * 64 + quad * 16 + mlow) * 8]);
      }
#pragma unroll
      for (int t = 0; t < 4; ++t)
#pragma unroll
        for (int u = 0; u < 4; ++u)
          acc[t][u] = __builtin_amdgcn_mfma_f32_16x16x32_bf16(a[t], b[u], acc[t][u], 0, 0, 0);
    }
  }

  const float* be = bias + (size_t)e * ND;
  if (MODE == 0) {
#pragma unroll
    for (int t = 0; t < 4; ++t) {
      int gr = row0 + wm * 64 + t * 16 + quad * 4;
#pragma unroll
      for (int u = 0; u < 4; ++u) {
        int gc = n0 + wn * 64 + u * 16 + mlow;
        float bv = be[gc];
#pragma unroll
        for (int r = 0; r < 4; ++r) {
          float h = acc[t][u][r] + bv;
          float g = 0.5f * h * (1.0f + erff(h * 0.70710678118654752f));
          Hout[(size_t)(gr + r) * ND + gc] = f2bf(g);
        }
      }
    }
  } else {
#pragma unroll
    for (int t = 0; t < 4; ++t) {
      int pr = row0 + wm * 64 + t * 16 + quad * 4;
#pragma unroll
      for (int r = 0; r < 4; ++r) {
        int p = pr + r;
        int tok = rows[p];
        float wt = wpos[p];
#pragma unroll
        for (int u = 0; u < 4; ++u) {
          int gc = n0 + wn * 64 + u * 16 + mlow;
          float val = wt * (acc[t][u][r] + be[gc]);
          atomicAdd(Oout + (size_t)tok * OUT_DIM + gc, val);
        }
      }
    }
  }
}

extern "C" void kernel_launch(void* const* d_in, const int* in_sizes, int n_in,
                              void* d_out, int out_size, void* d_ws, size_t ws_size,
                              hipStream_t stream) {
  const float* x      = (const float*)d_in[0];
  const float* gate_w = (const float*)d_in[1];
  const float* gate_b = (const float*)d_in[2];
  const float* w1     = (const float*)d_in[3];
  const float* b1     = (const float*)d_in[4];
  const float* w2     = (const float*)d_in[5];
  const float* b2     = (const float*)d_in[6];
  float* out = (float*)d_out;
  char* ws = (char*)d_ws;

  int*   cnt    = (int*)(ws + WS_CNT);
  int*   cursor = (int*)(ws + WS_CURSOR);
  int*   offs   = (int*)(ws + WS_OFFS);
  int*   rbe    = (int*)(ws + WS_RBE);
  int*   tkidx  = (int*)(ws + WS_TKIDX);
  float* tkw    = (float*)(ws + WS_TKW);
  int*   rows   = (int*)(ws + WS_ROWS);
  float* wpos   = (float*)(ws + WS_WPOS);
  short* w1t    = (short*)(ws + WS_W1T);
  short* w2t    = (short*)(ws + WS_W2T);
  short* xbf    = (short*)(ws + WS_XBF);
  short* h      = (short*)(ws + WS_H);

  hipMemsetAsync(ws, 0, 128, stream);                                    // cnt+cursor+offs
  hipMemsetAsync(d_out, 0, (size_t)out_size * sizeof(float), stream);    // out accumulated by atomics

  cvt_x<<<B_TOKENS * IN_DIM / (256 * 8), 256, 0, stream>>>(x, xbf);

  transpose_cvt<<<dim3(HID_DIM / 32, IN_DIM / 32, N_EXPERTS), 256, 0, stream>>>(w1, w1t, IN_DIM, HID_DIM);
  transpose_cvt<<<dim3(OUT_DIM / 32, HID_DIM / 32, N_EXPERTS), 256, 0, stream>>>(w2, w2t, HID_DIM, OUT_DIM);

  gate_kernel<<<B_TOKENS / 16, 256, 0, stream>>>(x, gate_w, gate_b, tkidx, tkw, cnt);

  offsets_kernel<<<1, 256, 0, stream>>>(cnt, offs, rbe, rows, wpos, out + (size_t)B_TOKENS * OUT_DIM);

  rank_kernel<<<NPAIRS / 1024, 1024, 0, stream>>>(tkidx, tkw, offs, cursor, rows, wpos);

  moe_gemm<IN_DIM, HID_DIM, 0, 1><<<(HID_DIM / 128) * MAX_RB, 256, 0, stream>>>(
      xbf, w1t, b1, rbe, rows, wpos, h, nullptr);

  moe_gemm<HID_DIM, OUT_DIM, 1, 0><<<(OUT_DIM / 128) * MAX_RB, 256, 0, stream>>>(
      h, w2t, b2, rbe, rows, wpos, nullptr, out);
}